// Round 1
// baseline (591.044 us; speedup 1.0000x reference)
//
#include <hip/hip_runtime.h>
#include <hip/hip_bf16.h>

#define HDIM 512
#define BDIM 1024
#define DDIM 256

typedef _Float16 half8 __attribute__((ext_vector_type(8)));
typedef _Float16 half4_ __attribute__((ext_vector_type(4)));
typedef float f32x4 __attribute__((ext_vector_type(4)));

__device__ __forceinline__ float ftanh(float x) {
    // tanh(x) = 1 - 2/(e^{2x}+1); exact at +/-inf, ~1e-7 abs error
    float e = __expf(2.0f * x);
    return 1.0f - 2.0f / (e + 1.0f);
}

// K0: Wah (f32 [H][H]) -> fp16
__global__ __launch_bounds__(256) void k_convert(const float* __restrict__ Wah,
                                                 _Float16* __restrict__ W16) {
    int i = (blockIdx.x * 256 + threadIdx.x) * 4;
    float4 v = *(const float4*)&Wah[i];
    half4_ h;
    h[0] = (_Float16)v.x; h[1] = (_Float16)v.y;
    h[2] = (_Float16)v.z; h[3] = (_Float16)v.w;
    *(half4_*)&W16[i] = h;
}

// K1: qb[b,g] = sum_k concat(h_tilde,c_t)[b,k] * Waq[g,k] + ba[g]   (fp32)
// grid 256 blocks (4 b each), 256 threads (2 g each)
__global__ __launch_bounds__(256) void k_qproj(const float* __restrict__ h_tilde,
                                               const float* __restrict__ c_t,
                                               const float* __restrict__ Waq,
                                               const float* __restrict__ ba,
                                               float* __restrict__ qb) {
    __shared__ float qs[4][1024];
    int t = threadIdx.x;
    int b0 = blockIdx.x * 4;
    #pragma unroll
    for (int p = 0; p < 4; p++) {
        int f4 = t + p * 256;           // float4 index 0..1023
        int e = f4 * 4;
        int row = e >> 10, k = e & 1023;
        float4 v;
        if (k < 512) v = *(const float4*)&h_tilde[(b0 + row) * 512 + k];
        else         v = *(const float4*)&c_t[(b0 + row) * 512 + k - 512];
        *(float4*)&qs[row][k] = v;
    }
    __syncthreads();
    int g0 = t, g1 = t + 256;
    float acc0[4] = {0.f, 0.f, 0.f, 0.f};
    float acc1[4] = {0.f, 0.f, 0.f, 0.f};
    const float4* w0p = (const float4*)&Waq[(size_t)g0 * 1024];
    const float4* w1p = (const float4*)&Waq[(size_t)g1 * 1024];
    #pragma unroll 4
    for (int k4 = 0; k4 < 256; k4++) {
        float4 w0 = w0p[k4];
        float4 w1 = w1p[k4];
        #pragma unroll
        for (int bb = 0; bb < 4; bb++) {
            float4 q = *(const float4*)&qs[bb][k4 * 4];
            acc0[bb] += q.x * w0.x + q.y * w0.y + q.z * w0.z + q.w * w0.w;
            acc1[bb] += q.x * w1.x + q.y * w1.y + q.z * w1.z + q.w * w1.w;
        }
    }
    #pragma unroll
    for (int bb = 0; bb < 4; bb++) {
        qb[(b0 + bb) * 512 + g0] = acc0[bb] + ba[g0];
        qb[(b0 + bb) * 512 + g1] = acc1[bb] + ba[g1];
    }
}

// K2: fused  hp = hist @ Wah.T (fp16 MFMA)  -> tanh(hp + qb) . v  -> logits[B*D]
// grid 4096 blocks (BM=64 rows of M=B*D, full N=512), 512 threads = 8 waves.
// Wave w owns cols [w*64, w*64+64). Tile K-step BK=32, mfma 16x16x32 f16.
__global__ __launch_bounds__(512) void k_logits(const float* __restrict__ hist,
                                                const float* __restrict__ qb,
                                                const _Float16* __restrict__ W16,
                                                const float* __restrict__ v_t,
                                                float* __restrict__ logits) {
    // padded rows: 40 halves (80 B) -> conflict-free b128 frag reads
    __shared__ _Float16 Xs[64 * 40];
    __shared__ _Float16 Ws[512 * 40];
    __shared__ float qbs[512];
    __shared__ float vs[512];
    __shared__ float red[8][64];

    int t = threadIdx.x;
    int wave = t >> 6, lane = t & 63;
    int l15 = lane & 15, l4 = lane >> 4;
    long m_base = (long)blockIdx.x * 64;
    int b = (int)(m_base >> 8);       // 64 | 256 -> one b per block

    qbs[t] = qb[b * 512 + t];
    vs[t] = v_t[t];

    f32x4 acc[4][4];
    #pragma unroll
    for (int i = 0; i < 4; i++)
        #pragma unroll
        for (int j = 0; j < 4; j++)
            acc[i][j] = (f32x4){0.f, 0.f, 0.f, 0.f};

    int xrow = t >> 3, xc4 = (t & 7) * 4;
    const float* xsrc = &hist[(m_base + xrow) * 512 + xc4];

    for (int k0 = 0; k0 < 512; k0 += 32) {
        __syncthreads();   // previous iteration's frag reads done
        // stage X tile: 64 rows x 32 k, fp32 -> fp16
        float4 xv = *(const float4*)(xsrc + k0);
        half4_ xh;
        xh[0] = (_Float16)xv.x; xh[1] = (_Float16)xv.y;
        xh[2] = (_Float16)xv.z; xh[3] = (_Float16)xv.w;
        *(half4_*)&Xs[xrow * 40 + xc4] = xh;
        // stage W tile: 512 rows x 32 k fp16, thread t -> row t (64 B)
        const _Float16* wsrc = &W16[t * 512 + k0];
        uint4 w0 = *(const uint4*)(wsrc + 0);
        uint4 w1 = *(const uint4*)(wsrc + 8);
        uint4 w2 = *(const uint4*)(wsrc + 16);
        uint4 w3 = *(const uint4*)(wsrc + 24);
        *(uint4*)&Ws[t * 40 + 0]  = w0;
        *(uint4*)&Ws[t * 40 + 8]  = w1;
        *(uint4*)&Ws[t * 40 + 16] = w2;
        *(uint4*)&Ws[t * 40 + 24] = w3;
        __syncthreads();
        // fragments: A row = lane&15, k = (lane>>4)*8 + j (k-perm cancels A vs B)
        half8 a[4], bf[4];
        #pragma unroll
        for (int i = 0; i < 4; i++)
            a[i] = *(const half8*)&Xs[(i * 16 + l15) * 40 + l4 * 8];
        #pragma unroll
        for (int j = 0; j < 4; j++)
            bf[j] = *(const half8*)&Ws[(wave * 64 + j * 16 + l15) * 40 + l4 * 8];
        #pragma unroll
        for (int i = 0; i < 4; i++)
            #pragma unroll
            for (int j = 0; j < 4; j++)
                acc[i][j] = __builtin_amdgcn_mfma_f32_16x16x32_f16(a[i], bf[j], acc[i][j], 0, 0, 0);
    }

    // epilogue: tanh + v-dot, reduce over cols
    // C/D map (m89-verified): col = lane&15, row = (lane>>4)*4 + r
    #pragma unroll
    for (int i = 0; i < 4; i++) {
        #pragma unroll
        for (int r = 0; r < 4; r++) {
            float s = 0.0f;
            #pragma unroll
            for (int j = 0; j < 4; j++) {
                int col = wave * 64 + j * 16 + l15;
                s += ftanh(acc[i][j][r] + qbs[col]) * vs[col];
            }
            s += __shfl_xor(s, 1, 64);
            s += __shfl_xor(s, 2, 64);
            s += __shfl_xor(s, 4, 64);
            s += __shfl_xor(s, 8, 64);
            if (l15 == 0) red[wave][i * 16 + l4 * 4 + r] = s;
        }
    }
    __syncthreads();
    if (t < 64) {
        float s = 0.0f;
        #pragma unroll
        for (int w = 0; w < 8; w++) s += red[w][t];
        logits[m_base + t] = s;
    }
}

// K3: per-b softmax over D=256 + e_t = alpha @ hist[b]   (fp32, memory-bound)
__global__ __launch_bounds__(256) void k_softmax_et(const float* __restrict__ hist,
                                                    const float* __restrict__ logits,
                                                    float* __restrict__ out) {
    __shared__ float as_[256];
    __shared__ float wred[4];
    int b = blockIdx.x, t = threadIdx.x;
    float l = logits[b * 256 + t];
    float m = l;
    m = fmaxf(m, __shfl_xor(m, 1, 64));
    m = fmaxf(m, __shfl_xor(m, 2, 64));
    m = fmaxf(m, __shfl_xor(m, 4, 64));
    m = fmaxf(m, __shfl_xor(m, 8, 64));
    m = fmaxf(m, __shfl_xor(m, 16, 64));
    m = fmaxf(m, __shfl_xor(m, 32, 64));
    if ((t & 63) == 0) wred[t >> 6] = m;
    __syncthreads();
    m = fmaxf(fmaxf(wred[0], wred[1]), fmaxf(wred[2], wred[3]));
    float e = __expf(l - m);
    float s = e;
    s += __shfl_xor(s, 1, 64);
    s += __shfl_xor(s, 2, 64);
    s += __shfl_xor(s, 4, 64);
    s += __shfl_xor(s, 8, 64);
    s += __shfl_xor(s, 16, 64);
    s += __shfl_xor(s, 32, 64);
    __syncthreads();               // all threads consumed wred (max) above
    if ((t & 63) == 0) wred[t >> 6] = s;
    __syncthreads();
    s = wred[0] + wred[1] + wred[2] + wred[3];
    float a = e / s;
    out[BDIM * HDIM + b * 256 + t] = a;   // alpha output
    as_[t] = a;
    __syncthreads();
    // e_t: thread t owns cols {2t, 2t+1}
    const float2* hb = (const float2*)&hist[(size_t)b * 256 * 512];
    float ax = 0.f, ay = 0.f;
    #pragma unroll 8
    for (int d = 0; d < 256; d++) {
        float2 h = hb[d * 256 + t];
        float al = as_[d];
        ax += al * h.x;
        ay += al * h.y;
    }
    float2 r; r.x = ax; r.y = ay;
    *(float2*)&out[b * 512 + 2 * t] = r;
}

extern "C" void kernel_launch(void* const* d_in, const int* in_sizes, int n_in,
                              void* d_out, int out_size, void* d_ws, size_t ws_size,
                              hipStream_t stream) {
    const float* h_tilde = (const float*)d_in[0];
    const float* c_t     = (const float*)d_in[1];
    const float* hist    = (const float*)d_in[2];
    const float* Waq     = (const float*)d_in[3];
    const float* Wah     = (const float*)d_in[4];
    const float* ba      = (const float*)d_in[5];
    const float* v_t     = (const float*)d_in[6];
    float* out = (float*)d_out;

    char* ws = (char*)d_ws;
    float*    qb     = (float*)ws;                                  // 2 MB
    _Float16* W16    = (_Float16*)(ws + (2u << 20));                // 512 KB
    float*    logits = (float*)(ws + (2u << 20) + (512u << 10));    // 1 MB

    k_convert<<<256, 256, 0, stream>>>(Wah, W16);
    k_qproj<<<256, 256, 0, stream>>>(h_tilde, c_t, Waq, ba, qb);
    k_logits<<<4096, 512, 0, stream>>>(hist, qb, W16, v_t, logits);
    k_softmax_et<<<1024, 256, 0, stream>>>(hist, logits, out);
}

// Round 2
// 490.774 us; speedup vs baseline: 1.2043x; 1.2043x over previous
//
#include <hip/hip_runtime.h>
#include <hip/hip_bf16.h>

#define HDIM 512
#define BDIM 1024
#define DDIM 256

typedef _Float16 half8 __attribute__((ext_vector_type(8)));
typedef _Float16 half4_ __attribute__((ext_vector_type(4)));
typedef float f32x4 __attribute__((ext_vector_type(4)));

__device__ __forceinline__ float ftanh(float x) {
    float e = __expf(2.0f * x);
    return 1.0f - 2.0f / (e + 1.0f);
}

// K0: Wah f32 [512][512] -> W16blk fp16, k-blocked [16][512][32]
// (each K-step's 32 KB W tile is contiguous -> perfectly coalesced loads)
__global__ __launch_bounds__(256) void k_convert(const float* __restrict__ Wah,
                                                 _Float16* __restrict__ W16blk) {
    int i = (blockIdx.x * 256 + threadIdx.x) * 4;
    int g = i >> 9, k = i & 511;
    float4 v = *(const float4*)&Wah[i];
    half4_ h;
    h[0] = (_Float16)v.x; h[1] = (_Float16)v.y;
    h[2] = (_Float16)v.z; h[3] = (_Float16)v.w;
    *(half4_*)&W16blk[((size_t)(k >> 5) * 512 + g) * 32 + (k & 31)] = h;
}

// K1: qb[b,g] = concat(h_tilde,c_t)[b,:] . Waq[g,:] + ba[g]   (fp32)
__global__ __launch_bounds__(256) void k_qproj(const float* __restrict__ h_tilde,
                                               const float* __restrict__ c_t,
                                               const float* __restrict__ Waq,
                                               const float* __restrict__ ba,
                                               float* __restrict__ qb) {
    __shared__ float qs[4][1024];
    int t = threadIdx.x;
    int b0 = blockIdx.x * 4;
    #pragma unroll
    for (int p = 0; p < 4; p++) {
        int f4 = t + p * 256;
        int e = f4 * 4;
        int row = e >> 10, k = e & 1023;
        float4 v;
        if (k < 512) v = *(const float4*)&h_tilde[(b0 + row) * 512 + k];
        else         v = *(const float4*)&c_t[(b0 + row) * 512 + k - 512];
        *(float4*)&qs[row][k] = v;
    }
    __syncthreads();
    int g0 = t, g1 = t + 256;
    float acc0[4] = {0.f, 0.f, 0.f, 0.f};
    float acc1[4] = {0.f, 0.f, 0.f, 0.f};
    const float4* w0p = (const float4*)&Waq[(size_t)g0 * 1024];
    const float4* w1p = (const float4*)&Waq[(size_t)g1 * 1024];
    #pragma unroll 4
    for (int k4 = 0; k4 < 256; k4++) {
        float4 w0 = w0p[k4];
        float4 w1 = w1p[k4];
        #pragma unroll
        for (int bb = 0; bb < 4; bb++) {
            float4 q = *(const float4*)&qs[bb][k4 * 4];
            acc0[bb] += q.x * w0.x + q.y * w0.y + q.z * w0.z + q.w * w0.w;
            acc1[bb] += q.x * w1.x + q.y * w1.y + q.z * w1.z + q.w * w1.w;
        }
    }
    #pragma unroll
    for (int bb = 0; bb < 4; bb++) {
        qb[(b0 + bb) * 512 + g0] = acc0[bb] + ba[g0];
        qb[(b0 + bb) * 512 + g1] = acc1[bb] + ba[g1];
    }
}

// K2: logits[m] = sum_g tanh( (hist @ Wah.T)[m,g] + qb[b,g] ) * v[g]
// BM=128, BN=512 (full N), 8 waves 1Mx8N, wave tile 128x64, BK=32.
// LDS double-buffered, ONE barrier per K-step, XOR-swizzled 16B granules.
template<int STORE16>
__global__ __launch_bounds__(512, 2) void k_logits(const float* __restrict__ hist,
                                                   const float* __restrict__ qb,
                                                   const _Float16* __restrict__ W16blk,
                                                   const float* __restrict__ v_t,
                                                   float* __restrict__ logits,
                                                   _Float16* __restrict__ hist16) {
    __shared__ _Float16 Xs[2][128 * 32];
    __shared__ _Float16 Ws[2][512 * 32];
    __shared__ float qbs[512];
    __shared__ float vs[512];
    __shared__ float red[8][128];

    int t = threadIdx.x;
    int w = t >> 6, lane = t & 63, l15 = lane & 15, l4 = lane >> 4;
    long m_base = (long)blockIdx.x * 128;
    int b = (int)(m_base >> 8);      // 128-row tile stays within one b (D=256)

    qbs[t] = qb[b * 512 + t];
    vs[t] = v_t[t];

    f32x4 acc[8][4];
    #pragma unroll
    for (int i = 0; i < 8; i++)
        #pragma unroll
        for (int j = 0; j < 4; j++)
            acc[i][j] = (f32x4){0.f, 0.f, 0.f, 0.f};

    // X staging: thread t owns (row = t>>2, 8 floats at k offset (t&3)*8)
    int xrow = t >> 2, xk = (t & 3) * 8;
    const float* xsrc = hist + (m_base + xrow) * 512 + xk;
    // LDS granule-swizzle: granule G = row*4 + kslot; G' = G ^ (row&7); addr = G'*8 halves
    int xg  = (t ^ ((t >> 2) & 7)) * 8;              // X: G = t exactly
    int wg0 = ((4 * t + 0) ^ (t & 7)) * 8;           // W: thread t owns row t
    int wg1 = ((4 * t + 1) ^ (t & 7)) * 8;
    int wg2 = ((4 * t + 2) ^ (t & 7)) * 8;
    int wg3 = ((4 * t + 3) ^ (t & 7)) * 8;
    const _Float16* wsrc = W16blk + (size_t)t * 32;  // + ks*16384 per step

    int x7 = l15 & 7;                                // = row&7 for all frag rows

    // prologue: load K-step 0
    float4 xr0 = *(const float4*)(xsrc);
    float4 xr1 = *(const float4*)(xsrc + 4);
    uint4 wr0 = *(const uint4*)(wsrc);
    uint4 wr1 = *(const uint4*)(wsrc + 8);
    uint4 wr2 = *(const uint4*)(wsrc + 16);
    uint4 wr3 = *(const uint4*)(wsrc + 24);

    #pragma unroll 2
    for (int ks = 0; ks < 16; ks++) {
        int cur = ks & 1;
        _Float16* xsh = Xs[cur];
        _Float16* wsh = Ws[cur];
        // convert + stage into buf[cur]
        half8 xh;
        xh[0] = (_Float16)xr0.x; xh[1] = (_Float16)xr0.y;
        xh[2] = (_Float16)xr0.z; xh[3] = (_Float16)xr0.w;
        xh[4] = (_Float16)xr1.x; xh[5] = (_Float16)xr1.y;
        xh[6] = (_Float16)xr1.z; xh[7] = (_Float16)xr1.w;
        *(half8*)&xsh[xg] = xh;
        *(uint4*)&wsh[wg0] = wr0;
        *(uint4*)&wsh[wg1] = wr1;
        *(uint4*)&wsh[wg2] = wr2;
        *(uint4*)&wsh[wg3] = wr3;
        if (STORE16)
            *(half8*)&hist16[(size_t)(m_base + xrow) * 512 + ks * 32 + xk] = xh;
        __syncthreads();
        // prefetch K-step ks+1 (latency hides under the MFMA section below)
        if (ks < 15) {
            const float* xs2 = xsrc + (ks + 1) * 32;
            xr0 = *(const float4*)(xs2);
            xr1 = *(const float4*)(xs2 + 4);
            const _Float16* ws2 = wsrc + (size_t)(ks + 1) * 16384;
            wr0 = *(const uint4*)(ws2);
            wr1 = *(const uint4*)(ws2 + 8);
            wr2 = *(const uint4*)(ws2 + 16);
            wr3 = *(const uint4*)(ws2 + 24);
        }
        // fragments (swizzled reads) + MFMA
        half8 a[8], bb[4];
        #pragma unroll
        for (int i = 0; i < 8; i++) {
            int row = i * 16 + l15;
            a[i] = *(const half8*)&xsh[((4 * row + l4) ^ x7) * 8];
        }
        #pragma unroll
        for (int j = 0; j < 4; j++) {
            int row = w * 64 + j * 16 + l15;
            bb[j] = *(const half8*)&wsh[((4 * row + l4) ^ x7) * 8];
        }
        #pragma unroll
        for (int i = 0; i < 8; i++)
            #pragma unroll
            for (int j = 0; j < 4; j++)
                acc[i][j] = __builtin_amdgcn_mfma_f32_16x16x32_f16(a[i], bb[j], acc[i][j], 0, 0, 0);
        // no second barrier: buf[cur] is next written at ks+2, after barrier(ks+1)
    }

    // epilogue: tanh + v-dot over this wave's 64 cols, reduce across l15 then waves
    #pragma unroll
    for (int i = 0; i < 8; i++) {
        #pragma unroll
        for (int r = 0; r < 4; r++) {
            float s = 0.0f;
            #pragma unroll
            for (int j = 0; j < 4; j++) {
                int col = w * 64 + j * 16 + l15;
                s += ftanh(acc[i][j][r] + qbs[col]) * vs[col];
            }
            s += __shfl_xor(s, 1, 64);
            s += __shfl_xor(s, 2, 64);
            s += __shfl_xor(s, 4, 64);
            s += __shfl_xor(s, 8, 64);
            if (l15 == 0) red[w][i * 16 + l4 * 4 + r] = s;
        }
    }
    __syncthreads();
    if (t < 128) {
        float s = 0.0f;
        #pragma unroll
        for (int ww = 0; ww < 8; ww++) s += red[ww][t];
        logits[m_base + t] = s;
    }
}

// K3: per-b softmax over D=256 + e_t = alpha @ hist[b]
template<int USE16>
__global__ __launch_bounds__(256) void k_softmax_et(const float* __restrict__ hist,
                                                    const _Float16* __restrict__ h16,
                                                    const float* __restrict__ logits,
                                                    float* __restrict__ out) {
    __shared__ float as_[256];
    __shared__ float wred[4];
    __shared__ float ered[512];
    int b = blockIdx.x, t = threadIdx.x;
    float l = logits[b * 256 + t];
    float m = l;
    m = fmaxf(m, __shfl_xor(m, 1, 64));
    m = fmaxf(m, __shfl_xor(m, 2, 64));
    m = fmaxf(m, __shfl_xor(m, 4, 64));
    m = fmaxf(m, __shfl_xor(m, 8, 64));
    m = fmaxf(m, __shfl_xor(m, 16, 64));
    m = fmaxf(m, __shfl_xor(m, 32, 64));
    if ((t & 63) == 0) wred[t >> 6] = m;
    __syncthreads();
    m = fmaxf(fmaxf(wred[0], wred[1]), fmaxf(wred[2], wred[3]));
    float e = __expf(l - m);
    float s = e;
    s += __shfl_xor(s, 1, 64);
    s += __shfl_xor(s, 2, 64);
    s += __shfl_xor(s, 4, 64);
    s += __shfl_xor(s, 8, 64);
    s += __shfl_xor(s, 16, 64);
    s += __shfl_xor(s, 32, 64);
    __syncthreads();
    if ((t & 63) == 0) wred[t >> 6] = s;
    __syncthreads();
    s = wred[0] + wred[1] + wred[2] + wred[3];
    float a = e / s;
    out[BDIM * HDIM + b * 256 + t] = a;      // alpha
    as_[t] = a;
    __syncthreads();
    // e_t: thread owns 4 cols, 2-way d-split (t>>7), partials combined via LDS
    int c4 = (t & 127) * 4;
    int dp = t >> 7;
    float e0 = 0.f, e1 = 0.f, e2 = 0.f, e3 = 0.f;
    if (USE16) {
        const _Float16* hb = h16 + (size_t)b * 256 * 512 + c4;
        #pragma unroll 4
        for (int d = dp; d < 256; d += 2) {
            float al = as_[d];
            half4_ h = *(const half4_*)&hb[(size_t)d * 512];
            e0 += al * (float)h[0]; e1 += al * (float)h[1];
            e2 += al * (float)h[2]; e3 += al * (float)h[3];
        }
    } else {
        const float* hb = hist + (size_t)b * 256 * 512 + c4;
        #pragma unroll 4
        for (int d = dp; d < 256; d += 2) {
            float al = as_[d];
            float4 h = *(const float4*)&hb[(size_t)d * 512];
            e0 += al * h.x; e1 += al * h.y; e2 += al * h.z; e3 += al * h.w;
        }
    }
    if (dp) {
        float4 v; v.x = e0; v.y = e1; v.z = e2; v.w = e3;
        *(float4*)&ered[c4] = v;
    }
    __syncthreads();
    if (!dp) {
        float4 p = *(const float4*)&ered[c4];
        float4 r; r.x = e0 + p.x; r.y = e1 + p.y; r.z = e2 + p.z; r.w = e3 + p.w;
        *(float4*)&out[b * 512 + c4] = r;
    }
}

extern "C" void kernel_launch(void* const* d_in, const int* in_sizes, int n_in,
                              void* d_out, int out_size, void* d_ws, size_t ws_size,
                              hipStream_t stream) {
    const float* h_tilde = (const float*)d_in[0];
    const float* c_t     = (const float*)d_in[1];
    const float* hist    = (const float*)d_in[2];
    const float* Waq     = (const float*)d_in[3];
    const float* Wah     = (const float*)d_in[4];
    const float* ba      = (const float*)d_in[5];
    const float* v_t     = (const float*)d_in[6];
    float* out = (float*)d_out;

    char* ws = (char*)d_ws;
    float*    qb     = (float*)ws;                                  // 2 MB
    _Float16* W16    = (_Float16*)(ws + (2u << 20));                // 512 KB
    float*    logits = (float*)(ws + (2u << 20) + (512u << 10));    // 1 MB
    _Float16* hist16 = (_Float16*)(ws + (4u << 20));                // 256 MB (optional)
    bool use16 = ws_size >= (size_t)(4u << 20) + ((size_t)BDIM * DDIM * HDIM * 2);

    k_convert<<<256, 256, 0, stream>>>(Wah, W16);
    k_qproj<<<256, 256, 0, stream>>>(h_tilde, c_t, Waq, ba, qb);
    if (use16) {
        k_logits<1><<<2048, 512, 0, stream>>>(hist, qb, W16, v_t, logits, hist16);
        k_softmax_et<1><<<1024, 256, 0, stream>>>(hist, hist16, logits, out);
    } else {
        k_logits<0><<<2048, 512, 0, stream>>>(hist, qb, W16, v_t, logits, hist16);
        k_softmax_et<0><<<1024, 256, 0, stream>>>(hist, hist16, logits, out);
    }
}

// Round 3
// 472.288 us; speedup vs baseline: 1.2514x; 1.0391x over previous
//
#include <hip/hip_runtime.h>
#include <hip/hip_bf16.h>

#define HDIM 512
#define BDIM 1024
#define DDIM 256
#define MTOT (BDIM * DDIM)

typedef _Float16 half8 __attribute__((ext_vector_type(8)));
typedef float f32x4 __attribute__((ext_vector_type(4)));

__device__ __forceinline__ float ftanh(float x) {
    float e = __expf(2.0f * x);
    return 1.0f - 2.0f / (e + 1.0f);
}

__device__ __forceinline__ void gl_lds16(const _Float16* src, _Float16* dst) {
    __builtin_amdgcn_global_load_lds((const __attribute__((address_space(1))) void*)src,
                                     (__attribute__((address_space(3))) void*)dst,
                                     16, 0, 0);
}

// K0: Wah f32 [512][512] -> W16L fp16, per-(nb,ks) 16KB chunks stored as the
// swizzled LDS image: natural granule (gc,s) lands at position (4*gc+s)^(gc&7).
// k_logits then DMAs each chunk linearly via global_load_lds.
__global__ __launch_bounds__(256) void k_convertW(const float* __restrict__ Wah,
                                                  _Float16* __restrict__ W16L) {
    int n = blockIdx.x * 256 + threadIdx.x;   // granule id, 32768 total
    int g = n >> 6, q = n & 63;               // row g, k-granule q (8 floats)
    int ks = q >> 2, s = q & 3;
    const float* src = Wah + (size_t)g * 512 + q * 8;
    float4 v0 = *(const float4*)(src);
    float4 v1 = *(const float4*)(src + 4);
    half8 h;
    h[0] = (_Float16)v0.x; h[1] = (_Float16)v0.y; h[2] = (_Float16)v0.z; h[3] = (_Float16)v0.w;
    h[4] = (_Float16)v1.x; h[5] = (_Float16)v1.y; h[6] = (_Float16)v1.z; h[7] = (_Float16)v1.w;
    int nb = g >> 8, gc = g & 255;
    size_t dst = ((size_t)(nb * 16 + ks) * 1024 + (size_t)((4 * gc + s) ^ (gc & 7))) * 8;
    *(half8*)&W16L[dst] = h;
}

// K1: qb[b,g] = concat(h_tilde,c_t)[b,:] . Waq[g,:] + ba[g]   (fp32)
__global__ __launch_bounds__(256) void k_qproj(const float* __restrict__ h_tilde,
                                               const float* __restrict__ c_t,
                                               const float* __restrict__ Waq,
                                               const float* __restrict__ ba,
                                               float* __restrict__ qb) {
    __shared__ float qs[4][1024];
    int t = threadIdx.x;
    int b0 = blockIdx.x * 4;
    #pragma unroll
    for (int p = 0; p < 4; p++) {
        int f4 = t + p * 256;
        int e = f4 * 4;
        int row = e >> 10, k = e & 1023;
        float4 v;
        if (k < 512) v = *(const float4*)&h_tilde[(b0 + row) * 512 + k];
        else         v = *(const float4*)&c_t[(b0 + row) * 512 + k - 512];
        *(float4*)&qs[row][k] = v;
    }
    __syncthreads();
    int g0 = t, g1 = t + 256;
    float acc0[4] = {0.f, 0.f, 0.f, 0.f};
    float acc1[4] = {0.f, 0.f, 0.f, 0.f};
    const float4* w0p = (const float4*)&Waq[(size_t)g0 * 1024];
    const float4* w1p = (const float4*)&Waq[(size_t)g1 * 1024];
    #pragma unroll 4
    for (int k4 = 0; k4 < 256; k4++) {
        float4 w0 = w0p[k4];
        float4 w1 = w1p[k4];
        #pragma unroll
        for (int bb = 0; bb < 4; bb++) {
            float4 q = *(const float4*)&qs[bb][k4 * 4];
            acc0[bb] += q.x * w0.x + q.y * w0.y + q.z * w0.z + q.w * w0.w;
            acc1[bb] += q.x * w1.x + q.y * w1.y + q.z * w1.z + q.w * w1.w;
        }
    }
    #pragma unroll
    for (int bb = 0; bb < 4; bb++) {
        qb[(b0 + bb) * 512 + g0] = acc0[bb] + ba[g0];
        qb[(b0 + bb) * 512 + g1] = acc1[bb] + ba[g1];
    }
}

// K2: partial logits. Block = 128 m-rows x 256 cols (nb = n-half), 256 thr,
// 4 waves 2Mx2N, wave tile 64x128. W staged via global_load_lds (DMA),
// X reg-staged with fp32->fp16 cvt. Double-buffered, ONE barrier/K-step.
template<int STORE16>
__global__ __launch_bounds__(256, 2) void k_logits(const float* __restrict__ hist,
                                                   const float* __restrict__ qb,
                                                   const _Float16* __restrict__ W16L,
                                                   const float* __restrict__ v_t,
                                                   float* __restrict__ logitsP,
                                                   _Float16* __restrict__ hist16) {
    __shared__ _Float16 Xs[2][512 * 8];    // 8 KB each, swizzled 16B granules
    __shared__ _Float16 Ws[2][1024 * 8];   // 16 KB each, DMA'd pre-swizzled
    __shared__ float qbs[256];
    __shared__ float vsh[256];
    __shared__ float red[2][128];

    int t = threadIdx.x;
    int w = t >> 6, lane = t & 63, l15 = lane & 15, l4 = lane >> 4;
    int bx = blockIdx.x;
    int mt = bx >> 1, nb = bx & 1;
    long m_base = (long)mt * 128;
    int b = mt >> 1;                       // 128-row tile within one b (D=256)
    int cbase = nb * 256;

    qbs[t] = qb[b * 512 + cbase + t];
    vsh[t] = v_t[cbase + t];

    f32x4 acc[4][8];
    #pragma unroll
    for (int i = 0; i < 4; i++)
        #pragma unroll
        for (int j = 0; j < 8; j++)
            acc[i][j] = (f32x4){0.f, 0.f, 0.f, 0.f};

    // X staging: thread t owns row t>>1, 16 floats at k offset (t&1)*16
    int xrow = t >> 1, koff = (t & 1) * 16;
    const float* xsrc = hist + (m_base + xrow) * 512 + koff;
    int s0 = (t & 1) * 2;
    int xg0 = ((4 * xrow + s0) ^ (xrow & 7)) * 8;
    int xg1 = ((4 * xrow + s0 + 1) ^ (xrow & 7)) * 8;
    _Float16* h16dst = hist16 + (m_base + xrow) * 512 + koff;

    const _Float16* wbase = W16L + (size_t)nb * 16 * 8192;   // + ks*8192

    // prologue: DMA W chunk ks=0, load X regs ks=0
    #pragma unroll
    for (int g = 0; g < 4; g++)
        gl_lds16(wbase + ((size_t)(w * 4 + g) * 64 + lane) * 8,
                 &Ws[0][(w * 4 + g) * 64 * 8]);
    float4 xr0 = *(const float4*)(xsrc + 0);
    float4 xr1 = *(const float4*)(xsrc + 4);
    float4 xr2 = *(const float4*)(xsrc + 8);
    float4 xr3 = *(const float4*)(xsrc + 12);

    int mr0 = (w >> 1) * 64, nh = w & 1;

    #pragma unroll 2
    for (int ks = 0; ks < 16; ks++) {
        int cur = ks & 1;
        _Float16* xsh = Xs[cur];
        _Float16* wsh = Ws[cur];
        // stage X (cvt + swizzled ds_write)
        half8 h0, h1;
        h0[0] = (_Float16)xr0.x; h0[1] = (_Float16)xr0.y; h0[2] = (_Float16)xr0.z; h0[3] = (_Float16)xr0.w;
        h0[4] = (_Float16)xr1.x; h0[5] = (_Float16)xr1.y; h0[6] = (_Float16)xr1.z; h0[7] = (_Float16)xr1.w;
        h1[0] = (_Float16)xr2.x; h1[1] = (_Float16)xr2.y; h1[2] = (_Float16)xr2.z; h1[3] = (_Float16)xr2.w;
        h1[4] = (_Float16)xr3.x; h1[5] = (_Float16)xr3.y; h1[6] = (_Float16)xr3.z; h1[7] = (_Float16)xr3.w;
        *(half8*)&xsh[xg0] = h0;
        *(half8*)&xsh[xg1] = h1;
        if (STORE16 && nb == 0) {
            *(half8*)(h16dst + ks * 32) = h0;
            *(half8*)(h16dst + ks * 32 + 8) = h1;
        }
        // barrier: waits W-DMA(ks) [issued last iter] + all X ds_writes
        __syncthreads();
        // issue next step's W DMA + X loads (hidden under MFMA below)
        if (ks < 15) {
            const _Float16* wk = wbase + (size_t)(ks + 1) * 8192;
            _Float16* wd = Ws[cur ^ 1];
            #pragma unroll
            for (int g = 0; g < 4; g++)
                gl_lds16(wk + ((size_t)(w * 4 + g) * 64 + lane) * 8,
                         &wd[(w * 4 + g) * 64 * 8]);
            const float* xs2 = xsrc + (ks + 1) * 32;
            xr0 = *(const float4*)(xs2 + 0);
            xr1 = *(const float4*)(xs2 + 4);
            xr2 = *(const float4*)(xs2 + 8);
            xr3 = *(const float4*)(xs2 + 12);
        }
        // fragments (swizzled reads) + MFMA
        half8 a[4], bb[8];
        #pragma unroll
        for (int i = 0; i < 4; i++) {
            int row = mr0 + i * 16 + l15;
            a[i] = *(const half8*)&xsh[((4 * row + l4) ^ (l15 & 7)) * 8];
        }
        #pragma unroll
        for (int j = 0; j < 8; j++) {
            int g = nh * 128 + j * 16 + l15;
            bb[j] = *(const half8*)&wsh[((4 * g + l4) ^ (l15 & 7)) * 8];
        }
        #pragma unroll
        for (int i = 0; i < 4; i++)
            #pragma unroll
            for (int j = 0; j < 8; j++)
                acc[i][j] = __builtin_amdgcn_mfma_f32_16x16x32_f16(a[i], bb[j], acc[i][j], 0, 0, 0);
    }

    // epilogue: tanh + v-dot over this wave's 128 cols
    // C/D map: col = lane&15 (within 16-col block), row = (lane>>4)*4 + r
    #pragma unroll
    for (int i = 0; i < 4; i++) {
        #pragma unroll
        for (int r = 0; r < 4; r++) {
            float s = 0.0f;
            #pragma unroll
            for (int j = 0; j < 8; j++) {
                int col = nh * 128 + j * 16 + l15;
                s += ftanh(acc[i][j][r] + qbs[col]) * vsh[col];
            }
            s += __shfl_xor(s, 1, 64);
            s += __shfl_xor(s, 2, 64);
            s += __shfl_xor(s, 4, 64);
            s += __shfl_xor(s, 8, 64);
            if (l15 == 0) red[nh][mr0 + i * 16 + l4 * 4 + r] = s;
        }
    }
    __syncthreads();
    if (t < 128)
        logitsP[(size_t)nb * MTOT + m_base + t] = red[0][t] + red[1][t];
}

// K3: per-b softmax over D=256 + e_t = alpha @ hist[b]
template<int USE16>
__global__ __launch_bounds__(256) void k_softmax_et(const float* __restrict__ hist,
                                                    const _Float16* __restrict__ h16,
                                                    const float* __restrict__ logitsP,
                                                    float* __restrict__ out) {
    __shared__ float as_[256];
    __shared__ float wred[4];
    __shared__ float ered[512];
    int b = blockIdx.x, t = threadIdx.x;
    float l = logitsP[b * 256 + t] + logitsP[MTOT + b * 256 + t];
    float m = l;
    m = fmaxf(m, __shfl_xor(m, 1, 64));
    m = fmaxf(m, __shfl_xor(m, 2, 64));
    m = fmaxf(m, __shfl_xor(m, 4, 64));
    m = fmaxf(m, __shfl_xor(m, 8, 64));
    m = fmaxf(m, __shfl_xor(m, 16, 64));
    m = fmaxf(m, __shfl_xor(m, 32, 64));
    if ((t & 63) == 0) wred[t >> 6] = m;
    __syncthreads();
    m = fmaxf(fmaxf(wred[0], wred[1]), fmaxf(wred[2], wred[3]));
    float e = __expf(l - m);
    float s = e;
    s += __shfl_xor(s, 1, 64);
    s += __shfl_xor(s, 2, 64);
    s += __shfl_xor(s, 4, 64);
    s += __shfl_xor(s, 8, 64);
    s += __shfl_xor(s, 16, 64);
    s += __shfl_xor(s, 32, 64);
    __syncthreads();
    if ((t & 63) == 0) wred[t >> 6] = s;
    __syncthreads();
    s = wred[0] + wred[1] + wred[2] + wred[3];
    float a = e / s;
    out[BDIM * HDIM + b * 256 + t] = a;      // alpha
    as_[t] = a;
    __syncthreads();
    // e_t: thread owns 4 cols, 2-way d-split, partials combined via LDS
    int c4 = (t & 127) * 4;
    int dp = t >> 7;
    float e0 = 0.f, e1 = 0.f, e2 = 0.f, e3 = 0.f;
    if (USE16) {
        const _Float16* hb = h16 + (size_t)b * 256 * 512 + c4;
        #pragma unroll 4
        for (int d = dp; d < 256; d += 2) {
            float al = as_[d];
            half8 hh;
            float4 hv = *(const float4*)&hb[(size_t)d * 512 - (c4 & 4)];
            // read aligned 16B containing our 4 halves
            hh = *(half8*)&hv;
            int o = (c4 & 4);
            e0 += al * (float)hh[o + 0]; e1 += al * (float)hh[o + 1];
            e2 += al * (float)hh[o + 2]; e3 += al * (float)hh[o + 3];
        }
    } else {
        const float* hb = hist + (size_t)b * 256 * 512 + c4;
        #pragma unroll 4
        for (int d = dp; d < 256; d += 2) {
            float al = as_[d];
            float4 h = *(const float4*)&hb[(size_t)d * 512];
            e0 += al * h.x; e1 += al * h.y; e2 += al * h.z; e3 += al * h.w;
        }
    }
    if (dp) {
        float4 v; v.x = e0; v.y = e1; v.z = e2; v.w = e3;
        *(float4*)&ered[c4] = v;
    }
    __syncthreads();
    if (!dp) {
        float4 p = *(const float4*)&ered[c4];
        float4 r; r.x = e0 + p.x; r.y = e1 + p.y; r.z = e2 + p.z; r.w = e3 + p.w;
        *(float4*)&out[b * 512 + c4] = r;
    }
}

extern "C" void kernel_launch(void* const* d_in, const int* in_sizes, int n_in,
                              void* d_out, int out_size, void* d_ws, size_t ws_size,
                              hipStream_t stream) {
    const float* h_tilde = (const float*)d_in[0];
    const float* c_t     = (const float*)d_in[1];
    const float* hist    = (const float*)d_in[2];
    const float* Waq     = (const float*)d_in[3];
    const float* Wah     = (const float*)d_in[4];
    const float* ba      = (const float*)d_in[5];
    const float* v_t     = (const float*)d_in[6];
    float* out = (float*)d_out;

    char* ws = (char*)d_ws;
    float*    qb      = (float*)ws;                               // 2 MB
    _Float16* W16L    = (_Float16*)(ws + (2u << 20));             // 512 KB
    float*    logitsP = (float*)(ws + (3u << 20));                // 2 MB (2 x 1 MB)
    _Float16* hist16  = (_Float16*)(ws + (8u << 20));             // 268 MB
    bool use16 = ws_size >= (size_t)(8u << 20) + ((size_t)BDIM * DDIM * HDIM * 2);

    k_convertW<<<128, 256, 0, stream>>>(Wah, W16L);
    k_qproj<<<256, 256, 0, stream>>>(h_tilde, c_t, Waq, ba, qb);
    if (use16) {
        k_logits<1><<<4096, 256, 0, stream>>>(hist, qb, W16L, v_t, logitsP, hist16);
        k_softmax_et<1><<<1024, 256, 0, stream>>>(hist, hist16, logitsP, out);
    } else {
        k_logits<0><<<4096, 256, 0, stream>>>(hist, qb, W16L, v_t, logitsP, hist16);
        k_softmax_et<0><<<1024, 256, 0, stream>>>(hist, hist16, logitsP, out);
    }
}

// Round 5
// 436.607 us; speedup vs baseline: 1.3537x; 1.0817x over previous
//
#include <hip/hip_runtime.h>
#include <hip/hip_bf16.h>

#define HDIM 512
#define BDIM 1024
#define DDIM 256
#define MTOT (BDIM * DDIM)

typedef _Float16 half8 __attribute__((ext_vector_type(8)));
typedef float f32x4 __attribute__((ext_vector_type(4)));

__device__ __forceinline__ float ftanh(float x) {
    float e = __expf(2.0f * x);
    return 1.0f - 2.0f / (e + 1.0f);
}

__device__ __forceinline__ void gl_lds16(const _Float16* src, _Float16* dst) {
    __builtin_amdgcn_global_load_lds((const __attribute__((address_space(1))) void*)src,
                                     (__attribute__((address_space(3))) void*)dst,
                                     16, 0, 0);
}

// K0: Wah f32 [512][512] -> W16 fp16, chunked layout:
// within chunk c (16 g-cols x 512 k = 8192 halves, contiguous):
//   granule index = kb*64 + g*4 + kp   (kb = k/32, kp = (k%32)/8)
//   holds Wah[c*16 + g][kb*32 + kp*8 .. +8]
// -> linear DMA via global_load_lds; B-frag read at granule kb*64 + l15*4 + l4
//    is 64 consecutive granules across the wave => conflict-free.
__global__ __launch_bounds__(256) void k_convertW(const float* __restrict__ Wah,
                                                  _Float16* __restrict__ W16) {
    int n = blockIdx.x * 256 + threadIdx.x;   // granule id, 32768 total
    int chunk = n >> 10, r = n & 1023;
    int kb = r >> 6, g = (r >> 2) & 15, kp = r & 3;
    const float* src = Wah + (size_t)(chunk * 16 + g) * 512 + kb * 32 + kp * 8;
    float4 v0 = *(const float4*)src;
    float4 v1 = *(const float4*)(src + 4);
    half8 h;
    h[0] = (_Float16)v0.x; h[1] = (_Float16)v0.y; h[2] = (_Float16)v0.z; h[3] = (_Float16)v0.w;
    h[4] = (_Float16)v1.x; h[5] = (_Float16)v1.y; h[6] = (_Float16)v1.z; h[7] = (_Float16)v1.w;
    *(half8*)&W16[(size_t)n * 8] = h;
}

// K1: qb[b,g] = concat(h_tilde,c_t)[b,:] . Waq[g,:] + ba[g]   (fp32)
__global__ __launch_bounds__(256) void k_qproj(const float* __restrict__ h_tilde,
                                               const float* __restrict__ c_t,
                                               const float* __restrict__ Waq,
                                               const float* __restrict__ ba,
                                               float* __restrict__ qb) {
    __shared__ float qs[4][1024];
    int t = threadIdx.x;
    int b0 = blockIdx.x * 4;
    #pragma unroll
    for (int p = 0; p < 4; p++) {
        int f4 = t + p * 256;
        int e = f4 * 4;
        int row = e >> 10, k = e & 1023;
        float4 v;
        if (k < 512) v = *(const float4*)&h_tilde[(b0 + row) * 512 + k];
        else         v = *(const float4*)&c_t[(b0 + row) * 512 + k - 512];
        *(float4*)&qs[row][k] = v;
    }
    __syncthreads();
    int g0 = t, g1 = t + 256;
    float acc0[4] = {0.f, 0.f, 0.f, 0.f};
    float acc1[4] = {0.f, 0.f, 0.f, 0.f};
    const float4* w0p = (const float4*)&Waq[(size_t)g0 * 1024];
    const float4* w1p = (const float4*)&Waq[(size_t)g1 * 1024];
    #pragma unroll 4
    for (int k4 = 0; k4 < 256; k4++) {
        float4 w0 = w0p[k4];
        float4 w1 = w1p[k4];
        #pragma unroll
        for (int bb = 0; bb < 4; bb++) {
            float4 q = *(const float4*)&qs[bb][k4 * 4];
            acc0[bb] += q.x * w0.x + q.y * w0.y + q.z * w0.z + q.w * w0.w;
            acc1[bb] += q.x * w1.x + q.y * w1.y + q.z * w1.z + q.w * w1.w;
        }
    }
    #pragma unroll
    for (int bb = 0; bb < 4; bb++) {
        qb[(b0 + bb) * 512 + g0] = acc0[bb] + ba[g0];
        qb[(b0 + bb) * 512 + g1] = acc1[bb] + ba[g1];
    }
}

// K2: logits[m] = sum_g tanh((hist @ Wah.T)[m,g] + qb[b,g]) * v[g]
// Block: 128 m-rows x full N=512. 256 thr / 4 waves, wave owns 32 rows.
// X: in REGISTERS as A-fragments (afr[2][16], loaded once, hist read once).
// W: streamed through LDS in 32 chunks (16 g x 512 k = 16 KB), double-buffered
//    via linear global_load_lds DMA; B-frag reads conflict-free by layout.
// Per chunk: 32 MFMA -> tanh+v fold into 8 running scalars/lane. 1 barrier/chunk.
__global__ __launch_bounds__(256, 2) void k_logits(const float* __restrict__ hist,
                                                   const float* __restrict__ qb,
                                                   const _Float16* __restrict__ W16,
                                                   const float* __restrict__ v_t,
                                                   float* __restrict__ logits) {
    __shared__ _Float16 Wb[2][8192];   // 16 KB each
    __shared__ float qbs[512];
    __shared__ float vsh[512];

    int t = threadIdx.x;
    int w = t >> 6, lane = t & 63, l15 = lane & 15, l4 = lane >> 4;
    size_t m_base = (size_t)blockIdx.x * 128;
    int b = (int)(m_base >> 8);        // one b per block (D=256, 128-row tile)

    qbs[t] = qb[b * 512 + t];
    qbs[t + 256] = qb[b * 512 + 256 + t];
    vsh[t] = v_t[t];
    vsh[t + 256] = v_t[256 + t];

    // issue DMA for chunk 0 (completes during X-load phase)
    #pragma unroll
    for (int g2 = 0; g2 < 4; g2++)
        gl_lds16(W16 + ((size_t)(w * 4 + g2) * 64 + lane) * 8,
                 &Wb[0][(w * 4 + g2) * 512]);

    // X-load phase: wave w owns rows [w*32, w*32+32); lane holds A-frags
    // afr[mf][kb] = X[m_base + w*32 + mf*16 + l15][kb*32 + l4*8 .. +8] as fp16
    half8 afr[2][16];
    const float* xb = hist + (m_base + w * 32 + l15) * 512 + l4 * 8;
    #pragma unroll
    for (int kb = 0; kb < 16; kb++) {
        #pragma unroll
        for (int mf = 0; mf < 2; mf++) {
            const float* p = xb + mf * 16 * 512 + kb * 32;
            float4 v0 = *(const float4*)p;
            float4 v1 = *(const float4*)(p + 4);
            half8 h;
            h[0] = (_Float16)v0.x; h[1] = (_Float16)v0.y; h[2] = (_Float16)v0.z; h[3] = (_Float16)v0.w;
            h[4] = (_Float16)v1.x; h[5] = (_Float16)v1.y; h[6] = (_Float16)v1.z; h[7] = (_Float16)v1.w;
            afr[mf][kb] = h;
        }
    }

    float S[2][4] = {{0.f, 0.f, 0.f, 0.f}, {0.f, 0.f, 0.f, 0.f}};

    __syncthreads();   // drains DMA chunk 0 (vmcnt) + LDS stores

    const int lofs = (l15 * 4 + l4) * 8;   // lane's granule within each kb-block

    for (int c = 0; c < 32; c++) {
        int cur = c & 1;
        // issue next chunk's DMA into the other buffer (in flight across this
        // whole chunk's MFMA section; drained by the barrier below)
        if (c < 31) {
            const _Float16* wc = W16 + (size_t)(c + 1) * 8192;
            #pragma unroll
            for (int g2 = 0; g2 < 4; g2++)
                gl_lds16(wc + ((size_t)(w * 4 + g2) * 64 + lane) * 8,
                         &Wb[cur ^ 1][(w * 4 + g2) * 512]);
        }
        const _Float16* bufp = &Wb[cur][lofs];
        f32x4 tac0 = (f32x4){0.f, 0.f, 0.f, 0.f};
        f32x4 tac1 = (f32x4){0.f, 0.f, 0.f, 0.f};
        __builtin_amdgcn_s_setprio(1);
        #pragma unroll
        for (int kb = 0; kb < 16; kb++) {
            half8 bf = *(const half8*)(bufp + kb * 512);   // kb-stride = 512 halves
            tac0 = __builtin_amdgcn_mfma_f32_16x16x32_f16(afr[0][kb], bf, tac0, 0, 0, 0);
            tac1 = __builtin_amdgcn_mfma_f32_16x16x32_f16(afr[1][kb], bf, tac1, 0, 0, 0);
        }
        __builtin_amdgcn_s_setprio(0);
        // fold: tanh + v-dot for this chunk's 16 cols (col = c*16 + l15)
        float qv = qbs[c * 16 + l15];
        float vv = vsh[c * 16 + l15];
        #pragma unroll
        for (int j = 0; j < 4; j++) {
            S[0][j] += ftanh(tac0[j] + qv) * vv;
            S[1][j] += ftanh(tac1[j] + qv) * vv;
        }
        __syncthreads();   // next DMA done; all waves done reading buf[cur]
    }

    // reduce over l15 (cols were spread across the 16 lanes of each l4 group)
    // output row = w*32 + mf*16 + l4*4 + j
    #pragma unroll
    for (int mf = 0; mf < 2; mf++) {
        #pragma unroll
        for (int j = 0; j < 4; j++) {
            float s = S[mf][j];
            s += __shfl_xor(s, 1, 64);
            s += __shfl_xor(s, 2, 64);
            s += __shfl_xor(s, 4, 64);
            s += __shfl_xor(s, 8, 64);
            if (l15 == 0)
                logits[m_base + w * 32 + mf * 16 + l4 * 4 + j] = s;
        }
    }
}

// K3: per-b softmax over D=256 + e_t = alpha @ hist[b]   (fp32, memory-bound)
__global__ __launch_bounds__(256) void k_softmax_et(const float* __restrict__ hist,
                                                    const float* __restrict__ logits,
                                                    float* __restrict__ out) {
    __shared__ float as_[256];
    __shared__ float wred[4];
    __shared__ float ered[512];
    int b = blockIdx.x, t = threadIdx.x;
    float l = logits[b * 256 + t];
    float m = l;
    m = fmaxf(m, __shfl_xor(m, 1, 64));
    m = fmaxf(m, __shfl_xor(m, 2, 64));
    m = fmaxf(m, __shfl_xor(m, 4, 64));
    m = fmaxf(m, __shfl_xor(m, 8, 64));
    m = fmaxf(m, __shfl_xor(m, 16, 64));
    m = fmaxf(m, __shfl_xor(m, 32, 64));
    if ((t & 63) == 0) wred[t >> 6] = m;
    __syncthreads();
    m = fmaxf(fmaxf(wred[0], wred[1]), fmaxf(wred[2], wred[3]));
    float e = __expf(l - m);
    float s = e;
    s += __shfl_xor(s, 1, 64);
    s += __shfl_xor(s, 2, 64);
    s += __shfl_xor(s, 4, 64);
    s += __shfl_xor(s, 8, 64);
    s += __shfl_xor(s, 16, 64);
    s += __shfl_xor(s, 32, 64);
    __syncthreads();
    if ((t & 63) == 0) wred[t >> 6] = s;
    __syncthreads();
    s = wred[0] + wred[1] + wred[2] + wred[3];
    float a = e / s;
    out[BDIM * HDIM + b * 256 + t] = a;      // alpha
    as_[t] = a;
    __syncthreads();
    // e_t: thread owns 4 cols, 2-way d-split, partials combined via LDS
    int c4 = (t & 127) * 4;
    int dp = t >> 7;
    float e0 = 0.f, e1 = 0.f, e2 = 0.f, e3 = 0.f;
    const float* hb = hist + (size_t)b * 256 * 512 + c4;
    #pragma unroll 4
    for (int d = dp; d < 256; d += 2) {
        float al = as_[d];
        float4 h = *(const float4*)&hb[(size_t)d * 512];
        e0 += al * h.x; e1 += al * h.y; e2 += al * h.z; e3 += al * h.w;
    }
    if (dp) {
        float4 v; v.x = e0; v.y = e1; v.z = e2; v.w = e3;
        *(float4*)&ered[c4] = v;
    }
    __syncthreads();
    if (!dp) {
        float4 p = *(const float4*)&ered[c4];
        float4 r; r.x = e0 + p.x; r.y = e1 + p.y; r.z = e2 + p.z; r.w = e3 + p.w;
        *(float4*)&out[b * 512 + c4] = r;
    }
}

extern "C" void kernel_launch(void* const* d_in, const int* in_sizes, int n_in,
                              void* d_out, int out_size, void* d_ws, size_t ws_size,
                              hipStream_t stream) {
    const float* h_tilde = (const float*)d_in[0];
    const float* c_t     = (const float*)d_in[1];
    const float* hist    = (const float*)d_in[2];
    const float* Waq     = (const float*)d_in[3];
    const float* Wah     = (const float*)d_in[4];
    const float* ba      = (const float*)d_in[5];
    const float* v_t     = (const float*)d_in[6];
    float* out = (float*)d_out;

    char* ws = (char*)d_ws;
    float*    qb     = (float*)ws;                               // 2 MB
    _Float16* W16    = (_Float16*)(ws + (2u << 20));             // 512 KB
    float*    logits = (float*)(ws + (3u << 20));                // 1 MB

    k_convertW<<<128, 256, 0, stream>>>(Wah, W16);
    k_qproj<<<256, 256, 0, stream>>>(h_tilde, c_t, Waq, ba, qb);
    k_logits<<<2048, 256, 0, stream>>>(hist, qb, W16, v_t, logits);
    k_softmax_et<<<1024, 256, 0, stream>>>(hist, logits, out);
}